// Round 1
// baseline (319.615 us; speedup 1.0000x reference)
//
#include <hip/hip_runtime.h>
#include <hip/hip_bf16.h>

typedef __attribute__((ext_vector_type(8))) short short8;     // 8 bf16 (4 VGPRs) MFMA A/B frag
typedef __attribute__((ext_vector_type(4))) float f32x4;      // MFMA C/D frag
typedef __attribute__((ext_vector_type(4))) unsigned short u16x4;

#define MFMA16(a, b, c) __builtin_amdgcn_mfma_f32_16x16x32_bf16((a), (b), (c), 0, 0, 0)

__device__ __forceinline__ unsigned short f2bf(float f) {
    union { float f; unsigned u; } v; v.f = f;
    return (unsigned short)((v.u + 0x7fffu + ((v.u >> 16) & 1u)) >> 16);
}

// ---------------------------------------------------------------- cast X -> bf16
__global__ void cast_x_kernel(const float* __restrict__ x, ushort* __restrict__ y) {
    int i = blockIdx.x * blockDim.x + threadIdx.x;      // one float4 per thread, exact grid
    float4 v = ((const float4*)x)[i];
    u16x4 o = { f2bf(v.x), f2bf(v.y), f2bf(v.z), f2bf(v.w) };
    *(u16x4*)(y + (size_t)i * 4) = o;
}

// ------------------------------------------- W [K][N] f32 -> WT [N][K] bf16
__global__ void transpose_cast_kernel(const float* __restrict__ W, ushort* __restrict__ WT,
                                      int K, int N) {
    __shared__ ushort t[64][66];                        // 66: odd word stride, conflict-free
    int n0 = blockIdx.x * 64, k0 = blockIdx.y * 64;
    int tn = threadIdx.x & 63, tg = threadIdx.x >> 6;
#pragma unroll
    for (int i = 0; i < 16; ++i) {
        int k = tg * 16 + i;
        t[tn][k] = f2bf(W[(size_t)(k0 + k) * N + n0 + tn]);
    }
    __syncthreads();
#pragma unroll
    for (int i = 0; i < 16; ++i) {
        int nn = tg * 16 + i;
        WT[(size_t)(n0 + nn) * K + k0 + tn] = t[nn][tn];
    }
}

// ---------------------------------------------------------------- GEMM C = A @ BT^T
// A [M][K] bf16 row-major, BT [N][K] bf16 (n-major). 128x128 tile, BK=64, 4 waves.
// MODE 0: QKV epilogue -> scatter Q (prescaled), K, VT (transposed V), bf16.
// MODE 1: proj epilogue -> Out fp32 [M][N].
#define QSCALE 0.18033688011112042f   /* 0.125 * log2(e) */

template <int MODE>
__global__ __launch_bounds__(256)
void gemm_bt_kernel(const ushort* __restrict__ A, const ushort* __restrict__ BT,
                    const float* __restrict__ bias,
                    ushort* __restrict__ Qb, ushort* __restrict__ Kb,
                    ushort* __restrict__ VT, float* __restrict__ Out,
                    int M, int N, int K) {
    __shared__ ushort Asm[128 * 64];
    __shared__ ushort Bsm[128 * 64];
    const int lane = threadIdx.x & 63;
    const int wv = threadIdx.x >> 6;
    const int l15 = lane & 15, lg = lane >> 4;
    const int rm = (wv >> 1) * 64, cn = (wv & 1) * 64;  // wave's 64x64 sub-tile
    const int row0 = blockIdx.y * 128, col0 = blockIdx.x * 128;

    const char* Agb = (const char*)(A + (size_t)row0 * K);
    const char* Bgb = (const char*)(BT + (size_t)col0 * K);
    const size_t rowbytes = (size_t)K * 2;

    f32x4 acc[4][4];
#pragma unroll
    for (int mi = 0; mi < 4; ++mi)
#pragma unroll
        for (int ni = 0; ni < 4; ++ni) acc[mi][ni] = f32x4{0.f, 0.f, 0.f, 0.f};

    const int grow_l = (lane >> 3);          // 0..7 within 8-row chunk
    const int gcol_l = (lane & 7) * 16;      // byte within 128B row

    for (int k0 = 0; k0 < K; k0 += 64) {
#pragma unroll
        for (int c = 0; c < 4; ++c) {
            int chunk = wv * 4 + c;                       // 16 chunks of 1KB
            size_t go = (size_t)(chunk * 8 + grow_l) * rowbytes + (size_t)k0 * 2 + gcol_l;
            int lo = chunk * 1024 + lane * 16;
            __builtin_amdgcn_global_load_lds(
                (const __attribute__((address_space(1))) void*)(Agb + go),
                (__attribute__((address_space(3))) void*)((char*)Asm + lo), 16, 0, 0);
            __builtin_amdgcn_global_load_lds(
                (const __attribute__((address_space(1))) void*)(Bgb + go),
                (__attribute__((address_space(3))) void*)((char*)Bsm + lo), 16, 0, 0);
        }
        __syncthreads();
#pragma unroll
        for (int ks = 0; ks < 2; ++ks) {
            short8 af[4], bf[4];
#pragma unroll
            for (int mi = 0; mi < 4; ++mi)
                af[mi] = *(const short8*)&Asm[(rm + mi * 16 + l15) * 64 + ks * 32 + lg * 8];
#pragma unroll
            for (int ni = 0; ni < 4; ++ni)
                bf[ni] = *(const short8*)&Bsm[(cn + ni * 16 + l15) * 64 + ks * 32 + lg * 8];
#pragma unroll
            for (int mi = 0; mi < 4; ++mi)
#pragma unroll
                for (int ni = 0; ni < 4; ++ni)
                    acc[mi][ni] = MFMA16(af[mi], bf[ni], acc[mi][ni]);
        }
        __syncthreads();
    }

    // Epilogue. D layout: lane holds D[(lg)*4+j][l15] (row=M dim, col=N dim).
    if (MODE == 0) {
        const int sect = col0 >> 10;   // 0=q 1=k 2=v, uniform per block (128 | 1024)
#pragma unroll
        for (int ni = 0; ni < 4; ++ni) {
            int col = col0 + cn + ni * 16 + l15;
            float bv = bias[col];
            int dcol = col & 1023, h = dcol >> 6, dd = dcol & 63;
#pragma unroll
            for (int mi = 0; mi < 4; ++mi) {
                int mrow0 = row0 + rm + mi * 16 + lg * 4;
                if (sect == 2) {
                    int b = mrow0 >> 11, s = mrow0 & 2047;   // 4 consecutive s, same b
                    u16x4 o;
#pragma unroll
                    for (int j = 0; j < 4; ++j) o[j] = f2bf(acc[mi][ni][j] + bv);
                    *(u16x4*)&VT[((size_t)((b << 4) + h) * 64 + dd) * 2048 + s] = o;
                } else {
                    ushort* dst = sect ? Kb : Qb;
                    float sc = sect ? 1.f : QSCALE;
#pragma unroll
                    for (int j = 0; j < 4; ++j) {
                        int tok = mrow0 + j;
                        int b = tok >> 11, s = tok & 2047;
                        dst[((size_t)((b << 4) + h) * 2048 + s) * 64 + dd] =
                            f2bf((acc[mi][ni][j] + bv) * sc);
                    }
                }
            }
        }
    } else {
#pragma unroll
        for (int ni = 0; ni < 4; ++ni) {
            int col = col0 + cn + ni * 16 + l15;
            float bv = bias[col];
#pragma unroll
            for (int mi = 0; mi < 4; ++mi) {
                int mrow0 = row0 + rm + mi * 16 + lg * 4;
#pragma unroll
                for (int j = 0; j < 4; ++j)
                    Out[(size_t)(mrow0 + j) * N + col] = acc[mi][ni][j] + bv;
            }
        }
    }
}

// ---------------------------------------------------------------- causal flash attention
// Q prescaled by 0.125*log2(e). Swapped QK^T: S^T = mfma(K, Q) so each lane owns
// one q-row (col = l15) -> row reduce = in-lane + shfl_xor(16,32).
// PV swapped: ctx^T = mfma(VT, P^T); P re-fragmented via per-wave LDS round trip.
__global__ __launch_bounds__(256)
void attn_kernel(const ushort* __restrict__ Qb, const ushort* __restrict__ Kb,
                 const ushort* __restrict__ VT, ushort* __restrict__ CTX) {
    __shared__ ushort Plds[4][16 * 32];                 // per-wave P tile [q=16][key=32]
    const int lane = threadIdx.x & 63;
    const int w = threadIdx.x >> 6;
    const int l15 = lane & 15, lg = lane >> 4;
    const int bh = blockIdx.y;                           // b*16 + h
    const int q0 = blockIdx.x * 64 + w * 16;             // wave's 16 q-rows

    const ushort* Qh = Qb + (size_t)bh * 2048 * 64;
    const ushort* Kh = Kb + (size_t)bh * 2048 * 64;
    const ushort* Vh = VT + (size_t)bh * 64 * 2048;

    const int qrow = q0 + l15;
    short8 qf0 = *(const short8*)&Qh[(size_t)qrow * 64 + lg * 8];
    short8 qf1 = *(const short8*)&Qh[(size_t)qrow * 64 + 32 + lg * 8];

    float mrun = -1e30f, lsum = 0.f;
    f32x4 acc[4];
#pragma unroll
    for (int t = 0; t < 4; ++t) acc[t] = f32x4{0.f, 0.f, 0.f, 0.f};

    const int nchunk = ((q0 + 15) >> 5) + 1;             // 32-key chunks up to diagonal
    for (int c = 0; c < nchunk; ++c) {
        const int kb = c * 32;
        f32x4 s0 = {0.f, 0.f, 0.f, 0.f}, s1 = {0.f, 0.f, 0.f, 0.f};
        {
            short8 kf;
            kf = *(const short8*)&Kh[(size_t)(kb + l15) * 64 + lg * 8];
            s0 = MFMA16(kf, qf0, s0);
            kf = *(const short8*)&Kh[(size_t)(kb + l15) * 64 + 32 + lg * 8];
            s0 = MFMA16(kf, qf1, s0);
            kf = *(const short8*)&Kh[(size_t)(kb + 16 + l15) * 64 + lg * 8];
            s1 = MFMA16(kf, qf0, s1);
            kf = *(const short8*)&Kh[(size_t)(kb + 16 + l15) * 64 + 32 + lg * 8];
            s1 = MFMA16(kf, qf1, s1);
        }
        // causal mask + online softmax (scores already in log2 domain)
        float tmax = -1e30f;
#pragma unroll
        for (int j = 0; j < 4; ++j) {
            int key = kb + lg * 4 + j;                   // lane holds S[qrow][key], S[qrow][key+16]
            s0[j] = (key <= qrow) ? s0[j] : -1e30f;
            s1[j] = (key + 16 <= qrow) ? s1[j] : -1e30f;
            tmax = fmaxf(tmax, fmaxf(s0[j], s1[j]));
        }
        tmax = fmaxf(tmax, __shfl_xor(tmax, 16));
        tmax = fmaxf(tmax, __shfl_xor(tmax, 32));
        float mnew = fmaxf(mrun, tmax);
        float scale = exp2f(mrun - mnew);
        float tsum = 0.f;
        u16x4 p0, p1;
#pragma unroll
        for (int j = 0; j < 4; ++j) {
            float e0 = exp2f(s0[j] - mnew);
            float e1 = exp2f(s1[j] - mnew);
            tsum += e0 + e1;
            p0[j] = f2bf(e0);
            p1[j] = f2bf(e1);
        }
        tsum += __shfl_xor(tsum, 16);
        tsum += __shfl_xor(tsum, 32);
        mrun = mnew;
        lsum = lsum * scale + tsum;
#pragma unroll
        for (int t = 0; t < 4; ++t) {
            acc[t][0] *= scale; acc[t][1] *= scale; acc[t][2] *= scale; acc[t][3] *= scale;
        }
        // P -> LDS [q][key], re-read as PV B-fragment (wave-local, no barrier needed)
        *(u16x4*)&Plds[w][l15 * 32 + lg * 4] = p0;
        *(u16x4*)&Plds[w][l15 * 32 + 16 + lg * 4] = p1;
        short8 pf = *(const short8*)&Plds[w][l15 * 32 + lg * 8];
#pragma unroll
        for (int t = 0; t < 4; ++t) {
            short8 vf = *(const short8*)&Vh[(size_t)(t * 16 + l15) * 2048 + kb + lg * 8];
            acc[t] = MFMA16(vf, pf, acc[t]);            // ctx^T[f = t*16+lg*4+j][q = l15]
        }
    }

    const float inv = 1.f / lsum;
    const int b = bh >> 4, h = bh & 15;
    const size_t tok = (size_t)b * 2048 + q0 + l15;
#pragma unroll
    for (int t = 0; t < 4; ++t) {
        u16x4 o;
#pragma unroll
        for (int j = 0; j < 4; ++j) o[j] = f2bf(acc[t][j] * inv);
        *(u16x4*)&CTX[tok * 1024 + (size_t)h * 64 + t * 16 + lg * 4] = o;
    }
}

// ----------------------------------------------------------------------------
extern "C" void kernel_launch(void* const* d_in, const int* in_sizes, int n_in,
                              void* d_out, int out_size, void* d_ws, size_t ws_size,
                              hipStream_t stream) {
    const float* X     = (const float*)d_in[0];   // [2,2048,1024]
    const float* Wqkv  = (const float*)d_in[1];   // [1024,3072]
    const float* bqkv  = (const float*)d_in[2];   // [3072]
    const float* Wproj = (const float*)d_in[3];   // [1024,1024]
    const float* bproj = (const float*)d_in[4];   // [1024]
    float* Out = (float*)d_out;                   // [2,2048,1024] fp32

    // workspace layout (bf16 elements), total ~48 MB
    ushort* Xb     = (ushort*)d_ws;
    ushort* WqkvT  = Xb + (size_t)4096 * 1024;
    ushort* WprojT = WqkvT + (size_t)3072 * 1024;
    ushort* Qb     = WprojT + (size_t)1024 * 1024;  // [b,h,s,d] prescaled
    ushort* Kb     = Qb + (size_t)4096 * 1024;      // [b,h,s,d]
    ushort* VT     = Kb + (size_t)4096 * 1024;      // [b,h,d,s]
    ushort* CTX    = VT + (size_t)4096 * 1024;      // [tok, 1024] merged heads

    cast_x_kernel<<<4096, 256, 0, stream>>>(X, Xb);
    transpose_cast_kernel<<<dim3(48, 16), 256, 0, stream>>>(Wqkv, WqkvT, 1024, 3072);
    transpose_cast_kernel<<<dim3(16, 16), 256, 0, stream>>>(Wproj, WprojT, 1024, 1024);
    gemm_bt_kernel<0><<<dim3(24, 32), 256, 0, stream>>>(Xb, WqkvT, bqkv, Qb, Kb, VT, nullptr,
                                                        4096, 3072, 1024);
    attn_kernel<<<dim3(32, 32), 256, 0, stream>>>(Qb, Kb, VT, CTX);
    gemm_bt_kernel<1><<<dim3(8, 32), 256, 0, stream>>>(CTX, WprojT, bproj, nullptr, nullptr,
                                                       nullptr, Out, 4096, 1024, 1024);
}

// Round 2
// 200.427 us; speedup vs baseline: 1.5947x; 1.5947x over previous
//
#include <hip/hip_runtime.h>
#include <hip/hip_bf16.h>

typedef __attribute__((ext_vector_type(8))) short short8;     // 8 bf16 (4 VGPRs) MFMA A/B frag
typedef __attribute__((ext_vector_type(4))) float f32x4;      // MFMA C/D frag
typedef __attribute__((ext_vector_type(4))) unsigned short u16x4;

#define MFMA16(a, b, c) __builtin_amdgcn_mfma_f32_16x16x32_bf16((a), (b), (c), 0, 0, 0)

__device__ __forceinline__ unsigned short f2bf(float f) {
    union { float f; unsigned u; } v; v.f = f;
    return (unsigned short)((v.u + 0x7fffu + ((v.u >> 16) & 1u)) >> 16);
}

// ---------------------------------------------------------------- cast X -> bf16
__global__ void cast_x_kernel(const float* __restrict__ x, ushort* __restrict__ y) {
    int i = blockIdx.x * blockDim.x + threadIdx.x;      // one float4 per thread, exact grid
    float4 v = ((const float4*)x)[i];
    u16x4 o = { f2bf(v.x), f2bf(v.y), f2bf(v.z), f2bf(v.w) };
    *(u16x4*)(y + (size_t)i * 4) = o;
}

// ------------------------------------------- W [K][N] f32 -> WT [N][K] bf16
__global__ void transpose_cast_kernel(const float* __restrict__ W, ushort* __restrict__ WT,
                                      int K, int N) {
    __shared__ ushort t[64][66];                        // 66: odd word stride, conflict-free
    int n0 = blockIdx.x * 64, k0 = blockIdx.y * 64;
    int tn = threadIdx.x & 63, tg = threadIdx.x >> 6;
#pragma unroll
    for (int i = 0; i < 16; ++i) {
        int k = tg * 16 + i;
        t[tn][k] = f2bf(W[(size_t)(k0 + k) * N + n0 + tn]);
    }
    __syncthreads();
#pragma unroll
    for (int i = 0; i < 16; ++i) {
        int nn = tg * 16 + i;
        WT[(size_t)(n0 + nn) * K + k0 + tn] = t[nn][tn];
    }
}

// ---------------------------------------------------------------- GEMM C = A @ BT^T
// A [M][K] bf16 row-major, BT [N][K] bf16 (n-major). 128x128 tile, BK=64, 4 waves.
// MODE 0: QKV epilogue -> scatter Q (prescaled), K, VT (transposed V), bf16.
// MODE 1: proj epilogue -> Out fp32 [M][N].
#define QSCALE 0.18033688011112042f   /* 0.125 * log2(e) */

template <int MODE>
__global__ __launch_bounds__(256)
void gemm_bt_kernel(const ushort* __restrict__ A, const ushort* __restrict__ BT,
                    const float* __restrict__ bias,
                    ushort* __restrict__ Qb, ushort* __restrict__ Kb,
                    ushort* __restrict__ VT, float* __restrict__ Out,
                    int M, int N, int K) {
    __shared__ ushort Asm[128 * 64];
    __shared__ ushort Bsm[128 * 64];
    const int lane = threadIdx.x & 63;
    const int wv = threadIdx.x >> 6;
    const int l15 = lane & 15, lg = lane >> 4;
    const int rm = (wv >> 1) * 64, cn = (wv & 1) * 64;  // wave's 64x64 sub-tile
    const int row0 = blockIdx.y * 128, col0 = blockIdx.x * 128;

    const char* Agb = (const char*)(A + (size_t)row0 * K);
    const char* Bgb = (const char*)(BT + (size_t)col0 * K);
    const size_t rowbytes = (size_t)K * 2;

    f32x4 acc[4][4];
#pragma unroll
    for (int mi = 0; mi < 4; ++mi)
#pragma unroll
        for (int ni = 0; ni < 4; ++ni) acc[mi][ni] = f32x4{0.f, 0.f, 0.f, 0.f};

    const int grow_l = (lane >> 3);          // 0..7 within 8-row chunk
    const int gcol_l = (lane & 7) * 16;      // byte within 128B row

    for (int k0 = 0; k0 < K; k0 += 64) {
#pragma unroll
        for (int c = 0; c < 4; ++c) {
            int chunk = wv * 4 + c;                       // 16 chunks of 1KB
            size_t go = (size_t)(chunk * 8 + grow_l) * rowbytes + (size_t)k0 * 2 + gcol_l;
            int lo = chunk * 1024 + lane * 16;
            __builtin_amdgcn_global_load_lds(
                (const __attribute__((address_space(1))) void*)(Agb + go),
                (__attribute__((address_space(3))) void*)((char*)Asm + lo), 16, 0, 0);
            __builtin_amdgcn_global_load_lds(
                (const __attribute__((address_space(1))) void*)(Bgb + go),
                (__attribute__((address_space(3))) void*)((char*)Bsm + lo), 16, 0, 0);
        }
        __syncthreads();
#pragma unroll
        for (int ks = 0; ks < 2; ++ks) {
            short8 af[4], bf[4];
#pragma unroll
            for (int mi = 0; mi < 4; ++mi)
                af[mi] = *(const short8*)&Asm[(rm + mi * 16 + l15) * 64 + ks * 32 + lg * 8];
#pragma unroll
            for (int ni = 0; ni < 4; ++ni)
                bf[ni] = *(const short8*)&Bsm[(cn + ni * 16 + l15) * 64 + ks * 32 + lg * 8];
#pragma unroll
            for (int mi = 0; mi < 4; ++mi)
#pragma unroll
                for (int ni = 0; ni < 4; ++ni)
                    acc[mi][ni] = MFMA16(af[mi], bf[ni], acc[mi][ni]);
        }
        __syncthreads();
    }

    // Epilogue. D layout: lane holds D[(lg)*4+j][l15] (row=M dim, col=N dim).
    if (MODE == 0) {
        const int sect = col0 >> 10;   // 0=q 1=k 2=v, uniform per block (128 | 1024)
#pragma unroll
        for (int ni = 0; ni < 4; ++ni) {
            int col = col0 + cn + ni * 16 + l15;
            float bv = bias[col];
            int dcol = col & 1023, h = dcol >> 6, dd = dcol & 63;
#pragma unroll
            for (int mi = 0; mi < 4; ++mi) {
                int mrow0 = row0 + rm + mi * 16 + lg * 4;
                if (sect == 2) {
                    int b = mrow0 >> 11, s = mrow0 & 2047;   // 4 consecutive s, same b
                    u16x4 o;
#pragma unroll
                    for (int j = 0; j < 4; ++j) o[j] = f2bf(acc[mi][ni][j] + bv);
                    *(u16x4*)&VT[((size_t)((b << 4) + h) * 64 + dd) * 2048 + s] = o;
                } else {
                    ushort* dst = sect ? Kb : Qb;
                    float sc = sect ? 1.f : QSCALE;
#pragma unroll
                    for (int j = 0; j < 4; ++j) {
                        int tok = mrow0 + j;
                        int b = tok >> 11, s = tok & 2047;
                        dst[((size_t)((b << 4) + h) * 2048 + s) * 64 + dd] =
                            f2bf((acc[mi][ni][j] + bv) * sc);
                    }
                }
            }
        }
    } else {
#pragma unroll
        for (int ni = 0; ni < 4; ++ni) {
            int col = col0 + cn + ni * 16 + l15;
            float bv = bias[col];
#pragma unroll
            for (int mi = 0; mi < 4; ++mi) {
                int mrow0 = row0 + rm + mi * 16 + lg * 4;
#pragma unroll
                for (int j = 0; j < 4; ++j)
                    Out[(size_t)(mrow0 + j) * N + col] = acc[mi][ni][j] + bv;
            }
        }
    }
}

// ---------------------------------------------------------------- causal flash attention v2
// Q prescaled by 0.125*log2(e). Swapped QK^T: S^T = mfma(K, Q), lane owns q-row l15.
// K/V chunk (32 keys) staged to LDS by the whole block via global_load_lds,
// double-buffered (2-phase pipeline). LDS reads XOR-swizzled via pre-swizzled
// global SOURCE addresses + swizzled READ offsets (linear LDS dest, rule #21).
// Block remap: heavy diagonal tiles first (LPT) + XCD-chunked so each XCD's
// blocks cover 4 heads (2MB K/V -> L2-resident).
__global__ __launch_bounds__(256)
void attn_kernel(const ushort* __restrict__ Qb, const ushort* __restrict__ Kb,
                 const ushort* __restrict__ VT, ushort* __restrict__ CTX) {
    __shared__ __align__(16) ushort Ksm[2][32 * 64];    // [key][d], 16B units XOR-swizzled
    __shared__ __align__(16) ushort Vsm[2][64 * 32];    // [f][key], 16B units XOR-swizzled
    __shared__ __align__(16) ushort Plds[4][16 * 40];   // per-wave P tile, padded row 40

    const int tid = threadIdx.x;
    const int lane = tid & 63;
    const int w = tid >> 6;
    const int l15 = lane & 15, lg = lane >> 4;

    // block remap: id = xcd + 8*(bh_lo*32 + (31-qt))
    const int id = blockIdx.x;
    const int xcd = id & 7, jj = id >> 3;
    const int bh = (xcd << 2) + (jj >> 5);               // 4 heads per XCD
    const int qt = 31 - (jj & 31);                       // heavy-first (LPT)
    const int q0 = qt * 64 + w * 16;                     // wave's 16 q-rows

    const ushort* Qh = Qb + (size_t)bh * 2048 * 64;
    const ushort* Kh = Kb + (size_t)bh * 2048 * 64;
    const ushort* Vh = VT + (size_t)bh * 64 * 2048;

    const int qrow = q0 + l15;
    short8 qf0 = *(const short8*)&Qh[(size_t)qrow * 64 + lg * 8];
    short8 qf1 = *(const short8*)&Qh[(size_t)qrow * 64 + 32 + lg * 8];

    float mrun = -1e30f, lsum = 0.f;
    f32x4 acc[4];
#pragma unroll
    for (int t = 0; t < 4; ++t) acc[t] = f32x4{0.f, 0.f, 0.f, 0.f};

    // stage thread-slot geometry (per thread: one 16B K slot, one 16B V slot)
    const int krow = tid >> 3, kc = tid & 7;             // K: [32 rows][8 x16B]
    const int ksw = (kc ^ (krow & 7)) * 8;               // pre-swizzled source col
    const int vf_ = tid >> 2, vc = tid & 3;              // V: [64 rows][4 x16B]
    const int vsw = (vc ^ ((vf_ >> 1) & 3)) * 8;

    const int nc = 2 * qt + 2;                           // 32-key chunks for this block

#define STAGE(buf, kb_)                                                                  \
    do {                                                                                 \
        const ushort* sK = Kh + (size_t)((kb_) + krow) * 64 + ksw;                       \
        __builtin_amdgcn_global_load_lds(                                                \
            (const __attribute__((address_space(1))) void*)sK,                           \
            (__attribute__((address_space(3))) void*)((char*)&Ksm[buf][0] + tid * 16),   \
            16, 0, 0);                                                                   \
        const ushort* sV = Vh + (size_t)vf_ * 2048 + (kb_) + vsw;                        \
        __builtin_amdgcn_global_load_lds(                                                \
            (const __attribute__((address_space(1))) void*)sV,                           \
            (__attribute__((address_space(3))) void*)((char*)&Vsm[buf][0] + tid * 16),   \
            16, 0, 0);                                                                   \
    } while (0)

    STAGE(0, 0);
    __syncthreads();

    const int r7 = l15 & 7;                              // K read swizzle key
    const int vs2 = (l15 >> 1) & 3;                      // V read swizzle key
    int cur = 0;

    for (int c = 0; c < nc; ++c) {
        const int kb = c * 32;
        if (c + 1 < nc) STAGE(cur ^ 1, kb + 32);

        const ushort* Kc = &Ksm[cur][0];
        const ushort* Vc = &Vsm[cur][0];

        // QK^T (swapped): s0 keys kb..kb+15, s1 keys kb+16..kb+31
        f32x4 s0 = {0.f, 0.f, 0.f, 0.f}, s1 = {0.f, 0.f, 0.f, 0.f};
        {
            short8 kf;
            kf = *(const short8*)&Kc[l15 * 64 + ((lg ^ r7) * 8)];
            s0 = MFMA16(kf, qf0, s0);
            kf = *(const short8*)&Kc[l15 * 64 + (((4 + lg) ^ r7) * 8)];
            s0 = MFMA16(kf, qf1, s0);
            kf = *(const short8*)&Kc[(16 + l15) * 64 + ((lg ^ r7) * 8)];
            s1 = MFMA16(kf, qf0, s1);
            kf = *(const short8*)&Kc[(16 + l15) * 64 + (((4 + lg) ^ r7) * 8)];
            s1 = MFMA16(kf, qf1, s1);
        }

        // causal mask + online softmax (log2 domain)
        float tmax = -1e30f;
#pragma unroll
        for (int j = 0; j < 4; ++j) {
            int key = kb + lg * 4 + j;                   // lane holds S[qrow][key], S[qrow][key+16]
            s0[j] = (key <= qrow) ? s0[j] : -1e30f;
            s1[j] = (key + 16 <= qrow) ? s1[j] : -1e30f;
            tmax = fmaxf(tmax, fmaxf(s0[j], s1[j]));
        }
        tmax = fmaxf(tmax, __shfl_xor(tmax, 16));
        tmax = fmaxf(tmax, __shfl_xor(tmax, 32));
        float mnew = fmaxf(mrun, tmax);
        float scale = exp2f(mrun - mnew);
        float tsum = 0.f;
        u16x4 p0, p1;
#pragma unroll
        for (int j = 0; j < 4; ++j) {
            float e0 = exp2f(s0[j] - mnew);
            float e1 = exp2f(s1[j] - mnew);
            tsum += e0 + e1;
            p0[j] = f2bf(e0);
            p1[j] = f2bf(e1);
        }
        tsum += __shfl_xor(tsum, 16);
        tsum += __shfl_xor(tsum, 32);
        mrun = mnew;
        lsum = lsum * scale + tsum;
#pragma unroll
        for (int t = 0; t < 4; ++t) {
            acc[t][0] *= scale; acc[t][1] *= scale; acc[t][2] *= scale; acc[t][3] *= scale;
        }

        // P -> LDS [q][key] (padded row 40), re-read as PV B-fragment (wave-local)
        *(u16x4*)&Plds[w][l15 * 40 + lg * 4] = p0;
        *(u16x4*)&Plds[w][l15 * 40 + 16 + lg * 4] = p1;
        short8 pf = *(const short8*)&Plds[w][l15 * 40 + lg * 8];
#pragma unroll
        for (int t = 0; t < 4; ++t) {
            short8 vf = *(const short8*)&Vc[(t * 16 + l15) * 32 + ((lg ^ vs2) * 8)];
            acc[t] = MFMA16(vf, pf, acc[t]);            // ctx^T[f = t*16+lg*4+j][q = l15]
        }

        __syncthreads();
        cur ^= 1;
    }
#undef STAGE

    const float inv = 1.f / lsum;
    const int b = bh >> 4, h = bh & 15;
    const size_t tok = (size_t)b * 2048 + q0 + l15;
#pragma unroll
    for (int t = 0; t < 4; ++t) {
        u16x4 o;
#pragma unroll
        for (int j = 0; j < 4; ++j) o[j] = f2bf(acc[t][j] * inv);
        *(u16x4*)&CTX[tok * 1024 + (size_t)h * 64 + t * 16 + lg * 4] = o;
    }
}

// ----------------------------------------------------------------------------
extern "C" void kernel_launch(void* const* d_in, const int* in_sizes, int n_in,
                              void* d_out, int out_size, void* d_ws, size_t ws_size,
                              hipStream_t stream) {
    const float* X     = (const float*)d_in[0];   // [2,2048,1024]
    const float* Wqkv  = (const float*)d_in[1];   // [1024,3072]
    const float* bqkv  = (const float*)d_in[2];   // [3072]
    const float* Wproj = (const float*)d_in[3];   // [1024,1024]
    const float* bproj = (const float*)d_in[4];   // [1024]
    float* Out = (float*)d_out;                   // [2,2048,1024] fp32

    // workspace layout (bf16 elements), total ~48 MB
    ushort* Xb     = (ushort*)d_ws;
    ushort* WqkvT  = Xb + (size_t)4096 * 1024;
    ushort* WprojT = WqkvT + (size_t)3072 * 1024;
    ushort* Qb     = WprojT + (size_t)1024 * 1024;  // [b,h,s,d] prescaled
    ushort* Kb     = Qb + (size_t)4096 * 1024;      // [b,h,s,d]
    ushort* VT     = Kb + (size_t)4096 * 1024;      // [b,h,d,s]
    ushort* CTX    = VT + (size_t)4096 * 1024;      // [tok, 1024] merged heads

    cast_x_kernel<<<4096, 256, 0, stream>>>(X, Xb);
    transpose_cast_kernel<<<dim3(48, 16), 256, 0, stream>>>(Wqkv, WqkvT, 1024, 3072);
    transpose_cast_kernel<<<dim3(16, 16), 256, 0, stream>>>(Wproj, WprojT, 1024, 1024);
    gemm_bt_kernel<0><<<dim3(24, 32), 256, 0, stream>>>(Xb, WqkvT, bqkv, Qb, Kb, VT, nullptr,
                                                        4096, 3072, 1024);
    attn_kernel<<<1024, 256, 0, stream>>>(Qb, Kb, VT, CTX);
    gemm_bt_kernel<1><<<dim3(8, 32), 256, 0, stream>>>(CTX, WprojT, bproj, nullptr, nullptr,
                                                       nullptr, Out, 4096, 1024, 1024);
}

// Round 4
// 168.592 us; speedup vs baseline: 1.8958x; 1.1888x over previous
//
#include <hip/hip_runtime.h>
#include <hip/hip_bf16.h>

typedef __attribute__((ext_vector_type(8))) short short8;     // 8 bf16 (4 VGPRs) MFMA A/B frag
typedef __attribute__((ext_vector_type(4))) float f32x4;      // 16x16 MFMA C/D frag
typedef __attribute__((ext_vector_type(16))) float f32x16;    // 32x32 MFMA C/D frag
typedef __attribute__((ext_vector_type(4))) unsigned short u16x4;
typedef __attribute__((ext_vector_type(4))) unsigned int u32x4;

#define MFMA16(a, b, c) __builtin_amdgcn_mfma_f32_16x16x32_bf16((a), (b), (c), 0, 0, 0)
#define MFMA32(a, b, c) __builtin_amdgcn_mfma_f32_32x32x16_bf16((a), (b), (c), 0, 0, 0)

__device__ __forceinline__ unsigned short f2bf(float f) {
    union { float f; unsigned u; } v; v.f = f;
    return (unsigned short)((v.u + 0x7fffu + ((v.u >> 16) & 1u)) >> 16);
}

__device__ __forceinline__ unsigned cvtpk(float lo, float hi_) {
    unsigned r;
    asm volatile("v_cvt_pk_bf16_f32 %0, %1, %2" : "=v"(r) : "v"(lo), "v"(hi_));
    return r;
}

// ---------------------------------------------------------------- cast X -> bf16
__global__ void cast_x_kernel(const float* __restrict__ x, ushort* __restrict__ y) {
    int i = blockIdx.x * blockDim.x + threadIdx.x;      // one float4 per thread, exact grid
    float4 v = ((const float4*)x)[i];
    u16x4 o = { f2bf(v.x), f2bf(v.y), f2bf(v.z), f2bf(v.w) };
    *(u16x4*)(y + (size_t)i * 4) = o;
}

// ------------------------------------------- W [K][N] f32 -> WT [N][K] bf16
__global__ void transpose_cast_kernel(const float* __restrict__ W, ushort* __restrict__ WT,
                                      int K, int N) {
    __shared__ ushort t[64][66];                        // 66: odd word stride, conflict-free
    int n0 = blockIdx.x * 64, k0 = blockIdx.y * 64;
    int tn = threadIdx.x & 63, tg = threadIdx.x >> 6;
#pragma unroll
    for (int i = 0; i < 16; ++i) {
        int k = tg * 16 + i;
        t[tn][k] = f2bf(W[(size_t)(k0 + k) * N + n0 + tn]);
    }
    __syncthreads();
#pragma unroll
    for (int i = 0; i < 16; ++i) {
        int nn = tg * 16 + i;
        WT[(size_t)(n0 + nn) * K + k0 + tn] = t[nn][tn];
    }
}

// ---------------------------------------------------------------- GEMM C = A @ BT^T
// A [M][K] bf16 row-major, BT [N][K] bf16 (n-major). 128x128 tile, BK=64, 4 waves.
// MODE 0: QKV epilogue -> scatter Q (prescaled), K, VT (transposed V), bf16.
// MODE 1: proj epilogue -> Out fp32 [M][N].
#define QSCALE 0.18033688011112042f   /* 0.125 * log2(e) */

template <int MODE>
__global__ __launch_bounds__(256)
void gemm_bt_kernel(const ushort* __restrict__ A, const ushort* __restrict__ BT,
                    const float* __restrict__ bias,
                    ushort* __restrict__ Qb, ushort* __restrict__ Kb,
                    ushort* __restrict__ VT, float* __restrict__ Out,
                    int M, int N, int K) {
    __shared__ ushort Asm[128 * 64];
    __shared__ ushort Bsm[128 * 64];
    const int lane = threadIdx.x & 63;
    const int wv = threadIdx.x >> 6;
    const int l15 = lane & 15, lg = lane >> 4;
    const int rm = (wv >> 1) * 64, cn = (wv & 1) * 64;  // wave's 64x64 sub-tile
    const int row0 = blockIdx.y * 128, col0 = blockIdx.x * 128;

    const char* Agb = (const char*)(A + (size_t)row0 * K);
    const char* Bgb = (const char*)(BT + (size_t)col0 * K);
    const size_t rowbytes = (size_t)K * 2;

    f32x4 acc[4][4];
#pragma unroll
    for (int mi = 0; mi < 4; ++mi)
#pragma unroll
        for (int ni = 0; ni < 4; ++ni) acc[mi][ni] = f32x4{0.f, 0.f, 0.f, 0.f};

    const int grow_l = (lane >> 3);          // 0..7 within 8-row chunk
    const int gcol_l = (lane & 7) * 16;      // byte within 128B row

    for (int k0 = 0; k0 < K; k0 += 64) {
#pragma unroll
        for (int c = 0; c < 4; ++c) {
            int chunk = wv * 4 + c;                       // 16 chunks of 1KB
            size_t go = (size_t)(chunk * 8 + grow_l) * rowbytes + (size_t)k0 * 2 + gcol_l;
            int lo = chunk * 1024 + lane * 16;
            __builtin_amdgcn_global_load_lds(
                (const __attribute__((address_space(1))) void*)(Agb + go),
                (__attribute__((address_space(3))) void*)((char*)Asm + lo), 16, 0, 0);
            __builtin_amdgcn_global_load_lds(
                (const __attribute__((address_space(1))) void*)(Bgb + go),
                (__attribute__((address_space(3))) void*)((char*)Bsm + lo), 16, 0, 0);
        }
        __syncthreads();
#pragma unroll
        for (int ks = 0; ks < 2; ++ks) {
            short8 af[4], bf[4];
#pragma unroll
            for (int mi = 0; mi < 4; ++mi)
                af[mi] = *(const short8*)&Asm[(rm + mi * 16 + l15) * 64 + ks * 32 + lg * 8];
#pragma unroll
            for (int ni = 0; ni < 4; ++ni)
                bf[ni] = *(const short8*)&Bsm[(cn + ni * 16 + l15) * 64 + ks * 32 + lg * 8];
#pragma unroll
            for (int mi = 0; mi < 4; ++mi)
#pragma unroll
                for (int ni = 0; ni < 4; ++ni)
                    acc[mi][ni] = MFMA16(af[mi], bf[ni], acc[mi][ni]);
        }
        __syncthreads();
    }

    // Epilogue. D layout: lane holds D[(lg)*4+j][l15] (row=M dim, col=N dim).
    if (MODE == 0) {
        const int sect = col0 >> 10;   // 0=q 1=k 2=v, uniform per block (128 | 1024)
#pragma unroll
        for (int ni = 0; ni < 4; ++ni) {
            int col = col0 + cn + ni * 16 + l15;
            float bv = bias[col];
            int dcol = col & 1023, h = dcol >> 6, dd = dcol & 63;
#pragma unroll
            for (int mi = 0; mi < 4; ++mi) {
                int mrow0 = row0 + rm + mi * 16 + lg * 4;
                if (sect == 2) {
                    int b = mrow0 >> 11, s = mrow0 & 2047;   // 4 consecutive s, same b
                    u16x4 o;
#pragma unroll
                    for (int j = 0; j < 4; ++j) o[j] = f2bf(acc[mi][ni][j] + bv);
                    *(u16x4*)&VT[((size_t)((b << 4) + h) * 64 + dd) * 2048 + s] = o;
                } else {
                    ushort* dst = sect ? Kb : Qb;
                    float sc = sect ? 1.f : QSCALE;
#pragma unroll
                    for (int j = 0; j < 4; ++j) {
                        int tok = mrow0 + j;
                        int b = tok >> 11, s = tok & 2047;
                        dst[((size_t)((b << 4) + h) * 2048 + s) * 64 + dd] =
                            f2bf((acc[mi][ni][j] + bv) * sc);
                    }
                }
            }
        }
    } else {
#pragma unroll
        for (int ni = 0; ni < 4; ++ni) {
            int col = col0 + cn + ni * 16 + l15;
            float bv = bias[col];
#pragma unroll
            for (int mi = 0; mi < 4; ++mi) {
                int mrow0 = row0 + rm + mi * 16 + lg * 4;
#pragma unroll
                for (int j = 0; j < 4; ++j)
                    Out[(size_t)(mrow0 + j) * N + col] = acc[mi][ni][j] + bv;
            }
        }
    }
}

// ---------------------------------------------------------------- causal flash attention v3b
// 4 waves x 32 q-rows (block = 128 q), KVBLK=64, 32x32x16 MFMA.
// Swapped QK^T: S^T = mfma(K,Q) -> lane owns q-row lane&31 (16 scores/lane/tile).
// P re-fragmented IN REGISTERS via v_cvt_pk_bf16_f32 + v_permlane32_swap_b32 (T12).
// permlane32_swap semantics: vdst[32+i] <-> vsrc[i]; so lanes 0-31 receive the
// partner's value in VSRC (pb), lanes 32-63 receive it in VDST (pa).
// Defer-max rescale THR=8 (T13). K/V double-buffered LDS via global_load_lds with
// XOR-swizzled source + swizzled reads (rule #21). Mask only diagonal chunk;
// waves 0/1 skip their fully-masked final chunk (barrier still taken).
__global__ __launch_bounds__(256)
void attn_kernel(const ushort* __restrict__ Qb, const ushort* __restrict__ Kb,
                 const ushort* __restrict__ VT, ushort* __restrict__ CTX) {
    __shared__ __align__(16) ushort Ksm[2][64 * 64];    // [key][d], 16B-unit XOR-swizzled
    __shared__ __align__(16) ushort Vsm[2][64 * 64];    // [d][key], 16B-unit XOR-swizzled

    const int tid = threadIdx.x;
    const int lane = tid & 63;
    const int w = tid >> 6;
    const int l31 = lane & 31;
    const int hi = lane >> 5;                            // 0/1
    const int r7 = l31 & 7;

    // block remap: 512 blocks = 8 xcd x (4 bh x 16 qt). LPT: heavy (big qt) first.
    const int id = blockIdx.x;
    const int xcd = id & 7, jj = id >> 3;
    const int bh = (xcd << 2) + (jj >> 4);               // 4 heads per XCD -> K/V L2-resident
    const int qt = 15 - (jj & 15);
    const int qw0 = qt * 128 + w * 32;                   // wave's 32 q-rows
    const int qrow = qw0 + l31;

    const ushort* Qh = Qb + (size_t)bh * 2048 * 64;
    const ushort* Kh = Kb + (size_t)bh * 2048 * 64;
    const ushort* Vh = VT + (size_t)bh * 64 * 2048;

    // Q fragments: B-operand of QK mfma: B[k=d][col=q] -> lane needs Q[qrow][dc*16+hi*8..+7]
    short8 qf[4];
#pragma unroll
    for (int dc = 0; dc < 4; ++dc)
        qf[dc] = *(const short8*)&Qh[(size_t)qrow * 64 + dc * 16 + hi * 8];

    // staging geometry: 256 threads x 2 slots x 16B per tile (64 rows x 128B)
    const int srow = tid >> 3;                           // 0..31
    const int kxor = ((tid & 7) ^ (srow & 7)) * 8;       // pre-swizzled source col (elems)
    const size_t offK = (size_t)srow * 64 + kxor;
    const size_t offV = (size_t)srow * 2048 + kxor;

#define GLL(src, dst) __builtin_amdgcn_global_load_lds(                                 \
        (const __attribute__((address_space(1))) void*)(src),                           \
        (__attribute__((address_space(3))) void*)(dst), 16, 0, 0)

#define STAGE(buf, kb_)                                                                 \
    do {                                                                                \
        const ushort* kp = Kh + (size_t)(kb_)*64 + offK;                                \
        GLL(kp, (char*)&Ksm[buf][0] + tid * 16);                                        \
        GLL(kp + 32 * 64, (char*)&Ksm[buf][0] + 4096 + tid * 16);                       \
        const ushort* vp = Vh + (kb_) + offV;                                           \
        GLL(vp, (char*)&Vsm[buf][0] + tid * 16);                                        \
        GLL(vp + (size_t)32 * 2048, (char*)&Vsm[buf][0] + 4096 + tid * 16);             \
    } while (0)

    const int nc = 2 * qt + 2;                           // 64-key chunks for this block
    const int cdiag = 2 * qt + (w >> 1);                 // wave's diagonal chunk

    STAGE(0, 0);
    __syncthreads();

    float mrun = -1e30f, lsum = 0.f;
    f32x16 acc0, acc1;                                   // ctx^T d-tiles 0..31 / 32..63
#pragma unroll
    for (int r = 0; r < 16; ++r) { acc0[r] = 0.f; acc1[r] = 0.f; }

    int cur = 0;
    for (int c = 0; c < nc; ++c) {
        const int kb = c * 64;
        if (c + 1 < nc) STAGE(cur ^ 1, kb + 64);

        if (!(w < 2 && c == nc - 1)) {                   // w0/1: last chunk fully masked
            const ushort* Kc = &Ksm[cur][0];
            const ushort* Vc = &Vsm[cur][0];

            // ---- QK^T: two 32x32 S-tiles (keys kb..+31, kb+32..+63)
            f32x16 st0, st1;
#pragma unroll
            for (int r = 0; r < 16; ++r) { st0[r] = 0.f; st1[r] = 0.f; }
#pragma unroll
            for (int dc = 0; dc < 4; ++dc) {
                short8 kf0 = *(const short8*)(Kc + l31 * 64 + (((dc * 2 + hi) ^ r7) << 3));
                short8 kf1 = *(const short8*)(Kc + (32 + l31) * 64 + (((dc * 2 + hi) ^ r7) << 3));
                st0 = MFMA32(kf0, qf[dc], st0);
                st1 = MFMA32(kf1, qf[dc], st1);
            }

            // ---- causal mask (diagonal chunk only); key = base + (r&3) + 8*(r>>2)
            if (c == cdiag) {
                const int base0 = kb + (hi << 2);
                const int base1 = kb + 32 + (hi << 2);
#pragma unroll
                for (int r = 0; r < 16; ++r) {
                    int k0 = base0 + ((r & 3) + 8 * (r >> 2));
                    int k1 = base1 + ((r & 3) + 8 * (r >> 2));
                    st0[r] = (k0 <= qrow) ? st0[r] : -1e30f;
                    st1[r] = (k1 <= qrow) ? st1[r] : -1e30f;
                }
            }

            // ---- online softmax (log2 domain), defer-max THR=8
            float tmax = st0[0];
#pragma unroll
            for (int r = 1; r < 16; ++r) tmax = fmaxf(tmax, st0[r]);
#pragma unroll
            for (int r = 0; r < 16; ++r) tmax = fmaxf(tmax, st1[r]);
            tmax = fmaxf(tmax, __shfl_xor(tmax, 32));    // partner holds other half of row

            if (!__all(tmax <= mrun + 8.0f)) {
                float mnew = fmaxf(mrun, tmax);
                float sc = exp2f(mrun - mnew);
#pragma unroll
                for (int r = 0; r < 16; ++r) { acc0[r] *= sc; acc1[r] *= sc; }
                lsum *= sc;
                mrun = mnew;
            }

            float tsum = 0.f;
#pragma unroll
            for (int r = 0; r < 16; ++r) { st0[r] = exp2f(st0[r] - mrun); tsum += st0[r]; }
#pragma unroll
            for (int r = 0; r < 16; ++r) { st1[r] = exp2f(st1[r] - mrun); tsum += st1[r]; }
            lsum += tsum;                                // partner partial merged at end

            // ---- P re-frag in registers + PV (T12)
            // Frag for k-chunk kc (keys 16kc+8hi..+7):
            //   hi=0 lane: [own c00, own c01, partner c00, partner c01]
            //   hi=1 lane: [partner c10, partner c11, own c10, own c11]
            // Exchange: hi=0 sends c10/c11, hi=1 sends c00/c01 (e0/e1);
            // after swap, lanes 0-31 receive in pb (vsrc), lanes 32-63 in pa (vdst).
#define MAKE_PFRAG(st, kcL, out)                                                        \
    do {                                                                                \
        unsigned c00 = cvtpk(st[8 * kcL + 0], st[8 * kcL + 1]);                         \
        unsigned c01 = cvtpk(st[8 * kcL + 2], st[8 * kcL + 3]);                         \
        unsigned c10 = cvtpk(st[8 * kcL + 4], st[8 * kcL + 5]);                         \
        unsigned c11 = cvtpk(st[8 * kcL + 6], st[8 * kcL + 7]);                         \
        unsigned e0 = hi ? c00 : c10, e1 = hi ? c01 : c11;                              \
        unsigned pa0 = e0, pb0 = e0, pa1 = e1, pb1 = e1;                                \
        asm volatile("v_permlane32_swap_b32 %0, %1" : "+v"(pa0), "+v"(pb0));            \
        asm volatile("v_permlane32_swap_b32 %0, %1" : "+v"(pa1), "+v"(pb1));            \
        unsigned rec0 = hi ? pa0 : pb0;                                                 \
        unsigned rec1 = hi ? pa1 : pb1;                                                 \
        u32x4 fw;                                                                       \
        fw.x = hi ? rec0 : c00;                                                         \
        fw.y = hi ? rec1 : c01;                                                         \
        fw.z = hi ? c10 : rec0;                                                         \
        fw.w = hi ? c11 : rec1;                                                         \
        out = __builtin_bit_cast(short8, fw);                                           \
    } while (0)

            short8 pf;
            // tile 0 (keys kb..kb+31): k-chunks 0,1
            MAKE_PFRAG(st0, 0, pf);
            {
                short8 v0 = *(const short8*)(Vc + l31 * 64 + ((hi ^ r7) << 3));
                short8 v1 = *(const short8*)(Vc + (32 + l31) * 64 + ((hi ^ r7) << 3));
                acc0 = MFMA32(v0, pf, acc0);
                acc1 = MFMA32(v1, pf, acc1);
            }
            MAKE_PFRAG(st0, 1, pf);
            {
                short8 v0 = *(const short8*)(Vc + l31 * 64 + (((2 + hi) ^ r7) << 3));
                short8 v1 = *(const short8*)(Vc + (32 + l31) * 64 + (((2 + hi) ^ r7) << 3));
                acc0 = MFMA32(v0, pf, acc0);
                acc1 = MFMA32(v1, pf, acc1);
            }
            // tile 1 (keys kb+32..kb+63): k-chunks 2,3
            MAKE_PFRAG(st1, 0, pf);
            {
                short8 v0 = *(const short8*)(Vc + l31 * 64 + (((4 + hi) ^ r7) << 3));
                short8 v1 = *(const short8*)(Vc + (32 + l31) * 64 + (((4 + hi) ^ r7) << 3));
                acc0 = MFMA32(v0, pf, acc0);
                acc1 = MFMA32(v1, pf, acc1);
            }
            MAKE_PFRAG(st1, 1, pf);
            {
                short8 v0 = *(const short8*)(Vc + l31 * 64 + (((6 + hi) ^ r7) << 3));
                short8 v1 = *(const short8*)(Vc + (32 + l31) * 64 + (((6 + hi) ^ r7) << 3));
                acc0 = MFMA32(v0, pf, acc0);
                acc1 = MFMA32(v1, pf, acc1);
            }
#undef MAKE_PFRAG
        }

        __syncthreads();
        cur ^= 1;
    }
#undef STAGE
#undef GLL

    lsum += __shfl_xor(lsum, 32);                        // merge partner halves
    const float inv = 1.f / lsum;
    const int b = bh >> 4, h = bh & 15;
    const size_t tokrow = ((size_t)b * 2048 + qw0 + l31) * 1024 + (size_t)h * 64;

#define WRITE_DT(accv, dt)                                                              \
    do {                                                                                \
        _Pragma("unroll")                                                               \
        for (int q2 = 0; q2 < 4; ++q2) {                                                \
            int d0 = dt * 32 + 8 * q2 + (hi << 2);                                      \
            u16x4 o;                                                                    \
            _Pragma("unroll")                                                           \
            for (int j = 0; j < 4; ++j) o[j] = f2bf(accv[4 * q2 + j] * inv);            \
            *(u16x4*)&CTX[tokrow + d0] = o;                                             \
        }                                                                               \
    } while (0)

    WRITE_DT(acc0, 0);
    WRITE_DT(acc1, 1);
#undef WRITE_DT
}

// ----------------------------------------------------------------------------
extern "C" void kernel_launch(void* const* d_in, const int* in_sizes, int n_in,
                              void* d_out, int out_size, void* d_ws, size_t ws_size,
                              hipStream_t stream) {
    const float* X     = (const float*)d_in[0];   // [2,2048,1024]
    const float* Wqkv  = (const float*)d_in[1];   // [1024,3072]
    const float* bqkv  = (const float*)d_in[2];   // [3072]
    const float* Wproj = (const float*)d_in[3];   // [1024,1024]
    const float* bproj = (const float*)d_in[4];   // [1024]
    float* Out = (float*)d_out;                   // [2,2048,1024] fp32

    // workspace layout (bf16 elements), total ~48 MB
    ushort* Xb     = (ushort*)d_ws;
    ushort* WqkvT  = Xb + (size_t)4096 * 1024;
    ushort* WprojT = WqkvT + (size_t)3072 * 1024;
    ushort* Qb     = WprojT + (size_t)1024 * 1024;  // [b,h,s,d] prescaled
    ushort* Kb     = Qb + (size_t)4096 * 1024;      // [b,h,s,d]
    ushort* VT     = Kb + (size_t)4096 * 1024;      // [b,h,d,s]
    ushort* CTX    = VT + (size_t)4096 * 1024;      // [tok, 1024] merged heads

    cast_x_kernel<<<4096, 256, 0, stream>>>(X, Xb);
    transpose_cast_kernel<<<dim3(48, 16), 256, 0, stream>>>(Wqkv, WqkvT, 1024, 3072);
    transpose_cast_kernel<<<dim3(16, 16), 256, 0, stream>>>(Wproj, WprojT, 1024, 1024);
    gemm_bt_kernel<0><<<dim3(24, 32), 256, 0, stream>>>(Xb, WqkvT, bqkv, Qb, Kb, VT, nullptr,
                                                        4096, 3072, 1024);
    attn_kernel<<<512, 256, 0, stream>>>(Qb, Kb, VT, CTX);
    gemm_bt_kernel<1><<<dim3(8, 32), 256, 0, stream>>>(CTX, WprojT, bproj, nullptr, nullptr,
                                                       nullptr, Out, 4096, 1024, 1024);
}